// Round 6
// baseline (147.488 us; speedup 1.0000x reference)
//
#include <hip/hip_runtime.h>
#include <math.h>

// Problem constants (setup_inputs: S=2048, U=10, D=256)
#define SS   2048
#define UU   10
#define DD   256
#define BB   (SS * UU)   // 20480 rows
#define EPSF 1e-8f

typedef __attribute__((ext_vector_type(8))) short   bf16x8;
typedef __attribute__((ext_vector_type(4))) float   floatx4;

__device__ static inline unsigned short f2bf(float f) {
    union { float f; unsigned u; } v; v.f = f;
    unsigned r = (v.u + 0x7FFFu + ((v.u >> 16) & 1u)) >> 16;  // RNE
    return (unsigned short)r;
}

// ---- Kernel 1 (fused prep): normalize rows -> Enb, centroid+normalize -> Cnb,
//      zero sumexp (and out). ----
__global__ __launch_bounds__(256) void prep_kernel(const float* __restrict__ E,
                                                   unsigned short* __restrict__ Enb,
                                                   unsigned short* __restrict__ Cnb,
                                                   float* __restrict__ sumexp,
                                                   float* __restrict__ out) {
    const int s   = blockIdx.x;
    const int wid = threadIdx.x >> 6, lane = threadIdx.x & 63;
    __shared__ float cent[4][256];
    __shared__ float part[4];

    if (threadIdx.x < UU) sumexp[s * UU + threadIdx.x] = 0.f;
    if (s == 0 && threadIdx.x == 0) out[0] = 0.f;

    float cp0 = 0.f, cp1 = 0.f, cp2 = 0.f, cp3 = 0.f;
    for (int u = wid; u < UU; u += 4) {
        const size_t roff = (size_t)(s * UU + u) * DD;
        float4 v = ((const float4*)(E + roff))[lane];
        float ssq = v.x * v.x + v.y * v.y + v.z * v.z + v.w * v.w;
#pragma unroll
        for (int off = 32; off; off >>= 1) ssq += __shfl_xor(ssq, off, 64);
        const float rinv = 1.0f / fmaxf(sqrtf(ssq), EPSF);
        ushort4 o;
        o.x = f2bf(v.x * rinv); o.y = f2bf(v.y * rinv);
        o.z = f2bf(v.z * rinv); o.w = f2bf(v.w * rinv);
        ((ushort4*)(Enb + roff))[lane] = o;
        cp0 += v.x; cp1 += v.y; cp2 += v.z; cp3 += v.w;
    }
    cent[wid][lane * 4 + 0] = cp0;
    cent[wid][lane * 4 + 1] = cp1;
    cent[wid][lane * 4 + 2] = cp2;
    cent[wid][lane * 4 + 3] = cp3;
    __syncthreads();

    const int d = threadIdx.x;
    const float c = (cent[0][d] + cent[1][d] + cent[2][d] + cent[3][d]) * 0.1f;
    float p = c * c;
#pragma unroll
    for (int off = 32; off; off >>= 1) p += __shfl_xor(p, off, 64);
    if (lane == 0) part[wid] = p;
    __syncthreads();
    const float tot = part[0] + part[1] + part[2] + part[3];
    const float rinv = 1.0f / fmaxf(sqrtf(tot), EPSF);
    Cnb[(size_t)s * DD + d] = f2bf(c * rinv);
}

// ---- Kernel 2: bf16 MFMA GEMM (Enb x Cnb^T) fused with exp-sum + pos ----
// Round-6: BARRIER-FREE K-loop, ZERO global_load_lds. Diagnosis: rounds 0-5
// are all capped by a ~7 B/cyc per-workgroup global_load_lds stream x ~2
// effective blocks/CU (invariant across all schedules). This version stops
// using that path:
//   - Block = 128 rows x 512 cols (grid 640 = 160 row-groups x 4 col-blocks).
//   - A-tile (128x256, 64 KB) staged ONCE per block via normal loads +
//     swizzled ds_write_b128, ONE __syncthreads. Swizzle: 16B granule g of
//     row r stored at slot g^(r&15) -> frag ds_read_b128 ~2-way conflicts.
//   - B (Cnb, 1 MB total: L2-resident per XCD) loaded straight to REGISTERS
//     with plain global_load_dwordx4 (16 coalesced 64B lines per instr),
//     double-buffered at the kk level. NO barriers, NO DMA in the K-loop;
//     4 waves fully independent -> latency hidden by compiler pipelining +
//     2 blocks/CU x 4 waves TLP.
//   - Per wave: 2 tiles of 64 cols; per kk: 4 B-loads + 8 ds_read + 32 MFMA.
//   - Epilogue: exp-sums reduced into LDS row accumulator; ONE global atomic
//     per row per block (4x fewer atomics).
#define RWS  128      // rows per block
#define CBLK 512      // cols per block (SS/CBLK = 4 col-blocks)
#define CT   64       // cols per tile (per wave: 2 tiles)

__global__ __launch_bounds__(256) void gemm_lse_kernel(const unsigned short* __restrict__ Enb,
                                                       const unsigned short* __restrict__ Cnb,
                                                       float* __restrict__ posArr,
                                                       float* __restrict__ sumexp) {
    __shared__ unsigned short As[RWS * DD];   // 64 KB, swizzled granules
    __shared__ float lsum[RWS];

    const int tid  = threadIdx.x;
    const int wid  = tid >> 6, lane = tid & 63;
    const int l15  = lane & 15, quad = lane >> 4;

    // XCD-bijective chunk swizzle: grid 640 = 8 XCDs x 80. Consecutive swz
    // share a row-group (col-siblings) -> A-panel fetched into ONE XCD's L2.
    const int swz = (blockIdx.x & 7) * 80 + (blockIdx.x >> 3);
    const int gb = swz >> 2;                 // row-group 0..159
    const int cb = swz & 3;                  // col-block 0..3
    const int row0 = gb * RWS;
    const int n0   = cb * CBLK;

    if (tid < RWS) lsum[tid] = 0.f;

    // ---- stage A once: 256 B/thread, swizzled ds_write_b128 ----
    {
        const int ar = tid >> 1, ah = tid & 1;
        const unsigned short* gsrc = Enb + (size_t)(row0 + ar) * DD + ah * 128;
        unsigned short* lbase = As + ar * 256;
#pragma unroll
        for (int j = 0; j < 16; ++j) {
            const int slot = (ah * 16 + j) ^ (ar & 15);
            *(int4*)(lbase + slot * 8) = *(const int4*)(gsrc + j * 8);
        }
    }
    __syncthreads();     // the ONLY barrier before the epilogue flush

    const int wc0 = n0 + wid * (2 * CT);     // wave's 128-col base

#pragma unroll
    for (int c = 0; c < 2; ++c) {
        const int ct0 = wc0 + c * CT;

        floatx4 acc[8][4];
#pragma unroll
        for (int i = 0; i < 8; ++i)
#pragma unroll
            for (int j = 0; j < 4; ++j) acc[i][j] = (floatx4){0.f, 0.f, 0.f, 0.f};

        // B fragment base: col = ct0 + nt*16 + l15, bytes kk*64 + quad*16
        const unsigned short* bbase[4];
#pragma unroll
        for (int nt = 0; nt < 4; ++nt)
            bbase[nt] = Cnb + (size_t)(ct0 + nt * 16 + l15) * DD + quad * 8;

        bf16x8 bb[2][4];
#pragma unroll
        for (int nt = 0; nt < 4; ++nt) bb[0][nt] = *(const bf16x8*)(bbase[nt]);

#pragma unroll
        for (int kk = 0; kk < 8; ++kk) {
            if (kk < 7) {
#pragma unroll
                for (int nt = 0; nt < 4; ++nt)
                    bb[(kk + 1) & 1][nt] = *(const bf16x8*)(bbase[nt] + (kk + 1) * 32);
            }
            bf16x8 af[8];
#pragma unroll
            for (int mt = 0; mt < 8; ++mt)
                af[mt] = *(const bf16x8*)(As + (mt * 16 + l15) * 256 +
                                          (((kk * 4 + quad) ^ l15) * 8));
#pragma unroll
            for (int mt = 0; mt < 8; ++mt)
#pragma unroll
                for (int nt = 0; nt < 4; ++nt)
                    acc[mt][nt] = __builtin_amdgcn_mfma_f32_16x16x32_bf16(
                        af[mt], bb[kk & 1][nt], acc[mt][nt], 0, 0, 0);
        }

        // per-tile epilogue: C/D layout col=l15 (n), row=quad*4+reg (m)
#pragma unroll
        for (int mt = 0; mt < 8; ++mt) {
            const int growb = row0 + mt * 16 + quad * 4;
            float rs[4] = {0.f, 0.f, 0.f, 0.f};
            int lbl[4];
#pragma unroll
            for (int r = 0; r < 4; ++r) lbl[r] = (growb + r) / UU;
#pragma unroll
            for (int nt = 0; nt < 4; ++nt) {
                const int col = ct0 + nt * 16 + l15;
#pragma unroll
                for (int r = 0; r < 4; ++r) {
                    const float sim = acc[mt][nt][r];
                    if (col == lbl[r]) {
                        posArr[growb + r] = sim;   // excluded from sum (-inf mask)
                    } else {
                        rs[r] += __expf(sim);
                    }
                }
            }
#pragma unroll
            for (int m = 1; m < 16; m <<= 1) {
#pragma unroll
                for (int r = 0; r < 4; ++r) rs[r] += __shfl_xor(rs[r], m, 64);
            }
            if (l15 == 0) {
#pragma unroll
                for (int r = 0; r < 4; ++r)
                    atomicAdd(&lsum[mt * 16 + quad * 4 + r], rs[r]);
            }
        }
    }

    __syncthreads();
    if (tid < RWS) atomicAdd(&sumexp[row0 + tid], lsum[tid]);
}

// ---- Kernel 3: single-pass finalize: mean of (-pos + log(sumexp)) ----
__global__ __launch_bounds__(256) void finalize_kernel(const float* __restrict__ posArr,
                                                       const float* __restrict__ sumexp,
                                                       float* __restrict__ out) {
    __shared__ float sred[256];
    const int tid = threadIdx.x;
    const int r = blockIdx.x * 256 + tid;
    sred[tid] = logf(sumexp[r]) - posArr[r];
    __syncthreads();
#pragma unroll
    for (int off = 128; off; off >>= 1) {
        if (tid < off) sred[tid] += sred[tid + off];
        __syncthreads();
    }
    if (tid == 0) atomicAdd(out, sred[0] * (1.0f / (float)BB));
}

extern "C" void kernel_launch(void* const* d_in, const int* in_sizes, int n_in,
                              void* d_out, int out_size, void* d_ws, size_t ws_size,
                              hipStream_t stream) {
    const float* E = (const float*)d_in[0];
    float* out = (float*)d_out;

    unsigned short* Enb = (unsigned short*)d_ws;            // BB*DD bf16 = 10.5 MB
    unsigned short* Cnb = Enb + (size_t)BB * DD;            // SS*DD bf16 = 1 MB
    float* posArr = (float*)(Cnb + (size_t)SS * DD);        // BB floats
    float* sumexp = posArr + BB;                            // BB floats (zeroed by prep)

    prep_kernel<<<SS, 256, 0, stream>>>(E, Enb, Cnb, sumexp, out);
    gemm_lse_kernel<<<(BB / RWS) * (SS / CBLK), 256, 0, stream>>>(Enb, Cnb, posArr, sumexp);
    finalize_kernel<<<BB / 256, 256, 0, stream>>>(posArr, sumexp, out);
}

// Round 7
// 121.449 us; speedup vs baseline: 1.2144x; 1.2144x over previous
//
#include <hip/hip_runtime.h>
#include <math.h>

// Problem constants (setup_inputs: S=2048, U=10, D=256)
#define SS   2048
#define UU   10
#define DD   256
#define BB   (SS * UU)   // 20480 rows
#define EPSF 1e-8f

typedef __attribute__((ext_vector_type(8))) short   bf16x8;
typedef __attribute__((ext_vector_type(4))) float   floatx4;

__device__ static inline unsigned short f2bf(float f) {
    union { float f; unsigned u; } v; v.f = f;
    unsigned r = (v.u + 0x7FFFu + ((v.u >> 16) & 1u)) >> 16;  // RNE
    return (unsigned short)r;
}

__device__ static inline void gl_lds16(const unsigned short* g, unsigned short* l) {
    // 16B per lane; LDS dest = wave-uniform base + lane*16
    __builtin_amdgcn_global_load_lds((const __attribute__((address_space(1))) void*)g,
                                     (__attribute__((address_space(3))) void*)l, 16, 0, 0);
}

// ---- Kernel 1 (fused prep): normalize rows -> Enb, centroid+normalize -> Cnb,
//      zero sumexp (and out). ----
__global__ __launch_bounds__(256) void prep_kernel(const float* __restrict__ E,
                                                   unsigned short* __restrict__ Enb,
                                                   unsigned short* __restrict__ Cnb,
                                                   float* __restrict__ sumexp,
                                                   float* __restrict__ out) {
    const int s   = blockIdx.x;
    const int wid = threadIdx.x >> 6, lane = threadIdx.x & 63;
    __shared__ float cent[4][256];
    __shared__ float part[4];

    if (threadIdx.x < UU) sumexp[s * UU + threadIdx.x] = 0.f;
    if (s == 0 && threadIdx.x == 0) out[0] = 0.f;

    float cp0 = 0.f, cp1 = 0.f, cp2 = 0.f, cp3 = 0.f;
    for (int u = wid; u < UU; u += 4) {
        const size_t roff = (size_t)(s * UU + u) * DD;
        float4 v = ((const float4*)(E + roff))[lane];
        float ssq = v.x * v.x + v.y * v.y + v.z * v.z + v.w * v.w;
#pragma unroll
        for (int off = 32; off; off >>= 1) ssq += __shfl_xor(ssq, off, 64);
        const float rinv = 1.0f / fmaxf(sqrtf(ssq), EPSF);
        ushort4 o;
        o.x = f2bf(v.x * rinv); o.y = f2bf(v.y * rinv);
        o.z = f2bf(v.z * rinv); o.w = f2bf(v.w * rinv);
        ((ushort4*)(Enb + roff))[lane] = o;
        cp0 += v.x; cp1 += v.y; cp2 += v.z; cp3 += v.w;
    }
    cent[wid][lane * 4 + 0] = cp0;
    cent[wid][lane * 4 + 1] = cp1;
    cent[wid][lane * 4 + 2] = cp2;
    cent[wid][lane * 4 + 3] = cp3;
    __syncthreads();

    const int d = threadIdx.x;
    const float c = (cent[0][d] + cent[1][d] + cent[2][d] + cent[3][d]) * 0.1f;
    float p = c * c;
#pragma unroll
    for (int off = 32; off; off >>= 1) p += __shfl_xor(p, off, 64);
    if (lane == 0) part[wid] = p;
    __syncthreads();
    const float tot = part[0] + part[1] + part[2] + part[3];
    const float rinv = 1.0f / fmaxf(sqrtf(tot), EPSF);
    Cnb[(size_t)s * DD + d] = f2bf(c * rinv);
}

// ---- Kernel 2: bf16 MFMA GEMM (Enb x Cnb^T) fused with exp-sum + pos ----
// Round-7: A-RESIDENT LDS + B-only staging. Evidence: per-stream gl_lds rate
// is ~5-8 B/cyc invariant across all schedules (R0-R5); per-CU rate scales
// only with co-resident streams and total staged bytes. So: cut staged bytes
// 328 -> 205 MB with the PROVEN R0 inner step untouched.
//   - Block = 128 rows x 4 B-panels of 128 cols (grid 640 = 160 x 4).
//   - Prologue: stage the ENTIRE A-panel (8 K-chunks, 64 KB) once via the
//     R0 staging map (16 gl_lds per wave).
//   - Per panel: 8 K-steps of the verbatim R0 2-barrier step, but staging
//     ONLY the 8 KB B-chunk (2 gl_lds/wave); A-frags read resident LDS.
//   - Epilogue: R3 cross-panel rs accumulator; one reduce+atomic pass per
//     block (atomics /4 vs R0).
// LDS = A 64 KB + B 8 KB = 72 KB -> 2 blocks/CU (matches measured residency).
#define BM  128
#define BN  128
#define BK  32
#define NCK 8            // DD / BK
#define NBN 4            // B-panels per block; grid = 160 * (16/NBN) = 640
#define ACH (BM * BK)    // 4096 shorts = 8 KB per A K-chunk

__device__ __forceinline__ void chunk_mfma(const unsigned short* Ab,
                                           const unsigned short* Bb,
                                           const int* aoff, const int* boff,
                                           floatx4 (&acc)[4][4]) {
    bf16x8 af[4], bfr[4];
#pragma unroll
    for (int t = 0; t < 4; ++t) af[t]  = *(const bf16x8*)(Ab + aoff[t]);
#pragma unroll
    for (int t = 0; t < 4; ++t) bfr[t] = *(const bf16x8*)(Bb + boff[t]);
#pragma unroll
    for (int mt = 0; mt < 4; ++mt)
#pragma unroll
        for (int nt = 0; nt < 4; ++nt)
            acc[mt][nt] = __builtin_amdgcn_mfma_f32_16x16x32_bf16(af[mt], bfr[nt], acc[mt][nt], 0, 0, 0);
}

__global__ __launch_bounds__(256) void gemm_lse_kernel(const unsigned short* __restrict__ Enb,
                                                       const unsigned short* __restrict__ Cnb,
                                                       float* __restrict__ posArr,
                                                       float* __restrict__ sumexp) {
    __shared__ unsigned short As[NCK * ACH];   // 64 KB: K-chunk k at As + k*ACH
    __shared__ unsigned short Bs[BN * BK];     // 8 KB single buffer

    const int tid  = threadIdx.x;
    const int wid  = tid >> 6, lane = tid & 63;
    const int l15  = lane & 15, quad = lane >> 4;
    const int wave_m = wid >> 1, wave_n = wid & 1;

    // grid 640 = 8 XCDs x 80 (bijective); within an XCD, panel-group runs
    // fastest so row-group A-panels localize in one XCD's L2.
    const int swz = (blockIdx.x & 7) * 80 + (blockIdx.x >> 3);
    const int bm  = swz >> 2;                 // 0..159
    const int bnb = (swz & 3) * NBN;          // panel group base (0,4,8,12)
    const int row0 = bm * BM;

    // R0 staging map: sub-chunk = 16 rows x 32k = 1 KB; lane -> row rl=lane>>2,
    // slot sl=lane&3; fetch logical granule sl^((rl>>1)&3) (pre-swizzled
    // global source, linear LDS dest -> consistent with fragment-read swizzle).
    const int rl = lane >> 2;
    const int gf = ((lane & 3) ^ ((rl >> 1) & 3)) * 8;

    // ---- prologue: stage the WHOLE A-panel (8 chunks x 8 sub-chunks; 16/wave) ----
#pragma unroll 1
    for (int j = 0; j < 16; ++j) {
        const int id = wid * 16 + j;          // 0..63, wave-uniform per iter
        const int k  = id >> 3;               // K-chunk 0..7
        const int c  = id & 7;                // row sub-chunk 0..7
        gl_lds16(Enb + (size_t)(row0 + c * 16 + rl) * DD + k * BK + gf,
                 As + k * ACH + c * 512);
    }

    // fragment offsets (within an 8 KB chunk): row r = wtile*16 + l15,
    // elem = r*BK + (quad^((l15>>1)&3))*8  -- verified conflict-free
    const int fswz = (quad ^ ((l15 >> 1) & 3)) * 8;
    int aoff[4], boff[4];
#pragma unroll
    for (int t = 0; t < 4; ++t) {
        aoff[t] = (wave_m * 64 + t * 16 + l15) * BK + fswz;
        boff[t] = (wave_n * 64 + t * 16 + l15) * BK + fswz;
    }

    // hoisted labels + cross-panel exp accumulators (R3 pattern)
    int lbl[4][4];
    float rs[4][4];
#pragma unroll
    for (int mt = 0; mt < 4; ++mt) {
        const int growb = row0 + wave_m * 64 + mt * 16 + quad * 4;
#pragma unroll
        for (int r = 0; r < 4; ++r) {
            lbl[mt][r] = (growb + r) / UU;
            rs[mt][r]  = 0.f;
        }
    }

    floatx4 acc[4][4];

#pragma unroll 1
    for (int bl = 0; bl < NBN; ++bl) {
        const int n0 = (bnb + bl) * BN;
        // B sub-chunks: c = wid*2 + i (0..7), rows c*16..+15 of the panel
        const unsigned short* gpb[2];
#pragma unroll
        for (int i = 0; i < 2; ++i) {
            const int c = wid * 2 + i;
            gpb[i] = Cnb + (size_t)(n0 + c * 16 + rl) * DD + gf;
        }

#pragma unroll
        for (int i = 0; i < 4; ++i)
#pragma unroll
            for (int j = 0; j < 4; ++j) acc[i][j] = (floatx4){0.f, 0.f, 0.f, 0.f};

        // R0 2-barrier K-step, B-only staging (8 KB/step); A chunk resident.
        for (int k = 0; k < NCK; ++k) {
            __syncthreads();                  // prior B reads done (and panel WAR)
#pragma unroll
            for (int i = 0; i < 2; ++i)
                gl_lds16(gpb[i] + k * BK, Bs + (wid * 2 + i) * 512);
            __syncthreads();                  // vmcnt drained: B (and A on k=0) landed
            chunk_mfma(As + k * ACH, Bs, aoff, boff, acc);
        }

        // per-panel epilogue: exp-accumulate into cross-panel rs
#pragma unroll
        for (int mt = 0; mt < 4; ++mt) {
            const int growb = row0 + wave_m * 64 + mt * 16 + quad * 4;
#pragma unroll
            for (int nt = 0; nt < 4; ++nt) {
                const int col = n0 + wave_n * 64 + nt * 16 + l15;
#pragma unroll
                for (int r = 0; r < 4; ++r) {
                    const float sim = acc[mt][nt][r];
                    if (col == lbl[mt][r]) {
                        posArr[growb + r] = sim;   // excluded from sum (-inf mask)
                    } else {
                        rs[mt][r] += __expf(sim);
                    }
                }
            }
        }
    }

    // once-per-block reduce + atomics (C/D layout: col=l15, row=quad*4+reg)
#pragma unroll
    for (int mt = 0; mt < 4; ++mt) {
        const int growb = row0 + wave_m * 64 + mt * 16 + quad * 4;
#pragma unroll
        for (int m = 1; m < 16; m <<= 1) {
#pragma unroll
            for (int r = 0; r < 4; ++r) rs[mt][r] += __shfl_xor(rs[mt][r], m, 64);
        }
        if (l15 == 0) {
#pragma unroll
            for (int r = 0; r < 4; ++r) atomicAdd(&sumexp[growb + r], rs[mt][r]);
        }
    }
}

// ---- Kernel 3: single-pass finalize: mean of (-pos + log(sumexp)) ----
__global__ __launch_bounds__(256) void finalize_kernel(const float* __restrict__ posArr,
                                                       const float* __restrict__ sumexp,
                                                       float* __restrict__ out) {
    __shared__ float sred[256];
    const int tid = threadIdx.x;
    const int r = blockIdx.x * 256 + tid;
    sred[tid] = logf(sumexp[r]) - posArr[r];
    __syncthreads();
#pragma unroll
    for (int off = 128; off; off >>= 1) {
        if (tid < off) sred[tid] += sred[tid + off];
        __syncthreads();
    }
    if (tid == 0) atomicAdd(out, sred[0] * (1.0f / (float)BB));
}

extern "C" void kernel_launch(void* const* d_in, const int* in_sizes, int n_in,
                              void* d_out, int out_size, void* d_ws, size_t ws_size,
                              hipStream_t stream) {
    const float* E = (const float*)d_in[0];
    float* out = (float*)d_out;

    unsigned short* Enb = (unsigned short*)d_ws;            // BB*DD bf16 = 10.5 MB
    unsigned short* Cnb = Enb + (size_t)BB * DD;            // SS*DD bf16 = 1 MB
    float* posArr = (float*)(Cnb + (size_t)SS * DD);        // BB floats
    float* sumexp = posArr + BB;                            // BB floats (zeroed by prep)

    prep_kernel<<<SS, 256, 0, stream>>>(E, Enb, Cnb, sumexp, out);
    gemm_lse_kernel<<<(BB / BM) * (SS / BN / NBN), 256, 0, stream>>>(Enb, Cnb, posArr, sumexp);
    finalize_kernel<<<BB / 256, 256, 0, stream>>>(posArr, sumexp, out);
}

// Round 8
// 114.718 us; speedup vs baseline: 1.2857x; 1.0587x over previous
//
#include <hip/hip_runtime.h>
#include <math.h>

// Problem constants (setup_inputs: S=2048, U=10, D=256)
#define SS   2048
#define UU   10
#define DD   256
#define BB   (SS * UU)   // 20480 rows
#define EPSF 1e-8f

typedef __attribute__((ext_vector_type(8))) short   bf16x8;
typedef __attribute__((ext_vector_type(4))) float   floatx4;

__device__ static inline unsigned short f2bf(float f) {
    union { float f; unsigned u; } v; v.f = f;
    unsigned r = (v.u + 0x7FFFu + ((v.u >> 16) & 1u)) >> 16;  // RNE
    return (unsigned short)r;
}

__device__ static inline void gl_lds16(const unsigned short* g, unsigned short* l) {
    // 16B per lane; LDS dest = wave-uniform base + lane*16
    __builtin_amdgcn_global_load_lds((const __attribute__((address_space(1))) void*)g,
                                     (__attribute__((address_space(3))) void*)l, 16, 0, 0);
}

// ---- Kernel 1 (prep, BW-optimized rewrite): normalize rows -> Enb,
//      centroid+normalize -> Cnb, zero sumexp/out.
// Old prep: 2048 blocks x 10KB work = latency/launch-bound (~15us inferred).
// New: 256 blocks; one wave owns 2 FULL speakers; each lane holds a float4
// column-slice of all 10 rows in REGISTERS (20 independent 16B loads/lane in
// flight), 10 interleaved 6-step shuffle reductions, vectorized writes.
// Same math, same RNE conversion -> bit-identical outputs. ----
__global__ __launch_bounds__(256) void prep_kernel(const float* __restrict__ E,
                                                   unsigned short* __restrict__ Enb,
                                                   unsigned short* __restrict__ Cnb,
                                                   float* __restrict__ sumexp,
                                                   float* __restrict__ out) {
    const int wid = threadIdx.x >> 6, lane = threadIdx.x & 63;

    if (threadIdx.x < 80) sumexp[blockIdx.x * 80 + threadIdx.x] = 0.f;
    if (blockIdx.x == 0 && threadIdx.x == 0) out[0] = 0.f;

#pragma unroll
    for (int sp2 = 0; sp2 < 2; ++sp2) {
        const int sp = blockIdx.x * 8 + wid * 2 + sp2;   // speaker id
        const float* rb = E + (size_t)sp * UU * DD + lane * 4;

        float4 v[UU];
#pragma unroll
        for (int u = 0; u < UU; ++u) v[u] = *(const float4*)(rb + u * DD);

        float ssq[UU];
#pragma unroll
        for (int u = 0; u < UU; ++u)
            ssq[u] = v[u].x * v[u].x + v[u].y * v[u].y + v[u].z * v[u].z + v[u].w * v[u].w;
#pragma unroll
        for (int off = 32; off; off >>= 1) {
#pragma unroll
            for (int u = 0; u < UU; ++u) ssq[u] += __shfl_xor(ssq[u], off, 64);
        }

        unsigned short* eb = Enb + (size_t)sp * UU * DD + lane * 4;
        float cx = 0.f, cy = 0.f, cz = 0.f, cw = 0.f;
#pragma unroll
        for (int u = 0; u < UU; ++u) {
            const float rinv = 1.0f / fmaxf(sqrtf(ssq[u]), EPSF);
            ushort4 o;
            o.x = f2bf(v[u].x * rinv); o.y = f2bf(v[u].y * rinv);
            o.z = f2bf(v[u].z * rinv); o.w = f2bf(v[u].w * rinv);
            *(ushort4*)(eb + u * DD) = o;
            cx += v[u].x; cy += v[u].y; cz += v[u].z; cw += v[u].w;
        }

        cx *= 0.1f; cy *= 0.1f; cz *= 0.1f; cw *= 0.1f;
        float cs = cx * cx + cy * cy + cz * cz + cw * cw;
#pragma unroll
        for (int off = 32; off; off >>= 1) cs += __shfl_xor(cs, off, 64);
        const float rinv = 1.0f / fmaxf(sqrtf(cs), EPSF);
        ushort4 oc;
        oc.x = f2bf(cx * rinv); oc.y = f2bf(cy * rinv);
        oc.z = f2bf(cz * rinv); oc.w = f2bf(cw * rinv);
        *(ushort4*)(Cnb + (size_t)sp * DD + lane * 4) = oc;
    }
}

// ---- Kernel 2: bf16 MFMA GEMM (Enb x Cnb^T) fused with exp-sum + pos ----
// R3 core VERBATIM (measured best, 45.3us): 128x128 tile, 2x2 waves, 4x4
// 16x16x32 tiles, BK=32 single-buffered 2-barrier step, swizzled LDS
// granules, NBN=2 panel loop, cross-panel rs accumulator. ONLY change:
// bijective XCD swizzle (1280 = 8 x 160) so the 8 blocks sharing an A-panel
// land on ONE XCD -> A-panel fetched into one L2 (FETCH 70.7 -> ~14 MB) and
// staging drains hit L2 instead of L3/HBM.
#define BM  128
#define BN  128
#define BK  32
#define NBN 2            // bn panels per block; grid = 160 * (16/NBN) = 1280

__device__ __forceinline__ void chunk_mfma(const unsigned short* Ab,
                                           const unsigned short* Bb,
                                           const int* aoff, const int* boff,
                                           floatx4 (&acc)[4][4]) {
    bf16x8 af[4], bfr[4];
#pragma unroll
    for (int t = 0; t < 4; ++t) af[t]  = *(const bf16x8*)(Ab + aoff[t]);
#pragma unroll
    for (int t = 0; t < 4; ++t) bfr[t] = *(const bf16x8*)(Bb + boff[t]);
#pragma unroll
    for (int mt = 0; mt < 4; ++mt)
#pragma unroll
        for (int nt = 0; nt < 4; ++nt)
            acc[mt][nt] = __builtin_amdgcn_mfma_f32_16x16x32_bf16(af[mt], bfr[nt], acc[mt][nt], 0, 0, 0);
}

__global__ __launch_bounds__(256) void gemm_lse_kernel(const unsigned short* __restrict__ Enb,
                                                       const unsigned short* __restrict__ Cnb,
                                                       float* __restrict__ posArr,
                                                       float* __restrict__ sumexp) {
    __shared__ unsigned short As[BM * BK];   // 8 KB, single-buffered
    __shared__ unsigned short Bs[BN * BK];   // 8 KB

    const int tid  = threadIdx.x;
    const int wid  = tid >> 6, lane = tid & 63;
    const int l15  = lane & 15, quad = lane >> 4;
    const int wave_m = wid >> 1, wave_n = wid & 1;

    // bijective XCD swizzle: grid 1280 = 8 XCDs x 160. Within an XCD, 8
    // consecutive swz share bm -> one A-panel per XCD L2, reused 8x.
    const int swz = (blockIdx.x & 7) * 160 + (blockIdx.x >> 3);
    const int bm  = swz >> 3;                 // 0..159
    const int bnb = (swz & 7) * NBN;          // panel group base
    const int row0 = bm * BM;

    // staging map: 16 sub-chunks of 1 KB (16 rows x 32k); A: c=0..7, B:
    // c=8..15; 4 per wave. lane -> row rl=lane>>2, slot sl=lane&3; fetch
    // logical granule sl^((rl>>1)&3) (pre-swizzled global source, linear LDS
    // dest -> consistent with the fragment-read swizzle).
    const int rl = lane >> 2;
    const int gf = ((lane & 3) ^ ((rl >> 1) & 3)) * 8;
    const unsigned short* gpA[4];
    unsigned short* lp[4];
    size_t goffB[4];
#pragma unroll
    for (int i = 0; i < 4; ++i) {
        const int c = wid * 4 + i;
        if (c < 8) {
            gpA[i]  = Enb + (size_t)(row0 + c * 16 + rl) * DD + gf;
            lp[i]   = As + c * 512;
            goffB[i] = 0;
        } else {
            gpA[i]  = nullptr;
            lp[i]   = Bs + (c - 8) * 512;
            goffB[i] = (size_t)((c - 8) * 16 + rl) * DD + gf;
        }
    }

    // fragment offsets: row r = wtile*16 + l15, elem = r*BK + (quad^((l15>>1)&3))*8
    const int fswz = (quad ^ ((l15 >> 1) & 3)) * 8;
    int aoff[4], boff[4];
#pragma unroll
    for (int t = 0; t < 4; ++t) {
        aoff[t] = (wave_m * 64 + t * 16 + l15) * BK + fswz;
        boff[t] = (wave_n * 64 + t * 16 + l15) * BK + fswz;
    }

    // hoisted labels + cross-panel exp accumulators
    int lbl[4][4];
    float rs[4][4];
#pragma unroll
    for (int mt = 0; mt < 4; ++mt) {
        const int growb = row0 + wave_m * 64 + mt * 16 + quad * 4;
#pragma unroll
        for (int r = 0; r < 4; ++r) {
            lbl[mt][r] = (growb + r) / UU;
            rs[mt][r]  = 0.f;
        }
    }

    floatx4 acc[4][4];

#pragma unroll
    for (int bl = 0; bl < NBN; ++bl) {
        const int n0 = (bnb + bl) * BN;
        const unsigned short* gp[4];
#pragma unroll
        for (int i = 0; i < 4; ++i) {
            const int c = wid * 4 + i;
            gp[i] = (c < 8) ? gpA[i] : (Cnb + (size_t)n0 * DD + goffB[i]);
        }

#pragma unroll
        for (int i = 0; i < 4; ++i)
#pragma unroll
            for (int j = 0; j < 4; ++j) acc[i][j] = (floatx4){0.f, 0.f, 0.f, 0.f};

        // R0/R3 K-loop verbatim: sync; stage; sync; compute
        for (int k0 = 0; k0 < DD; k0 += BK) {
            __syncthreads();                      // prior LDS reads done
#pragma unroll
            for (int i = 0; i < 4; ++i) gl_lds16(gp[i] + k0, lp[i]);
            __syncthreads();                      // vmcnt drained: tiles landed
            chunk_mfma(As, Bs, aoff, boff, acc);
        }

        // per-panel epilogue: exp-accumulate into cross-panel rs
#pragma unroll
        for (int mt = 0; mt < 4; ++mt) {
            const int growb = row0 + wave_m * 64 + mt * 16 + quad * 4;
#pragma unroll
            for (int nt = 0; nt < 4; ++nt) {
                const int col = n0 + wave_n * 64 + nt * 16 + l15;
#pragma unroll
                for (int r = 0; r < 4; ++r) {
                    const float sim = acc[mt][nt][r];
                    if (col == lbl[mt][r]) {
                        posArr[growb + r] = sim;     // excluded from sum
                    } else {
                        rs[mt][r] += __expf(sim);
                    }
                }
            }
        }
    }

    // once-per-block reduce + atomics (C/D layout: col=l15, row=quad*4+reg)
#pragma unroll
    for (int mt = 0; mt < 4; ++mt) {
        const int growb = row0 + wave_m * 64 + mt * 16 + quad * 4;
#pragma unroll
        for (int m = 1; m < 16; m <<= 1) {
#pragma unroll
            for (int r = 0; r < 4; ++r) rs[mt][r] += __shfl_xor(rs[mt][r], m, 64);
        }
        if (l15 == 0) {
#pragma unroll
            for (int r = 0; r < 4; ++r) atomicAdd(&sumexp[growb + r], rs[mt][r]);
        }
    }
}

// ---- Kernel 3: single-pass finalize: mean of (-pos + log(sumexp)) ----
__global__ __launch_bounds__(256) void finalize_kernel(const float* __restrict__ posArr,
                                                       const float* __restrict__ sumexp,
                                                       float* __restrict__ out) {
    __shared__ float sred[256];
    const int tid = threadIdx.x;
    const int r = blockIdx.x * 256 + tid;
    sred[tid] = logf(sumexp[r]) - posArr[r];
    __syncthreads();
#pragma unroll
    for (int off = 128; off; off >>= 1) {
        if (tid < off) sred[tid] += sred[tid + off];
        __syncthreads();
    }
    if (tid == 0) atomicAdd(out, sred[0] * (1.0f / (float)BB));
}

extern "C" void kernel_launch(void* const* d_in, const int* in_sizes, int n_in,
                              void* d_out, int out_size, void* d_ws, size_t ws_size,
                              hipStream_t stream) {
    const float* E = (const float*)d_in[0];
    float* out = (float*)d_out;

    unsigned short* Enb = (unsigned short*)d_ws;            // BB*DD bf16 = 10.5 MB
    unsigned short* Cnb = Enb + (size_t)BB * DD;            // SS*DD bf16 = 1 MB
    float* posArr = (float*)(Cnb + (size_t)SS * DD);        // BB floats
    float* sumexp = posArr + BB;                            // BB floats (zeroed by prep)

    prep_kernel<<<SS / 8, 256, 0, stream>>>(E, Enb, Cnb, sumexp, out);
    gemm_lse_kernel<<<(BB / BM) * (SS / BN / NBN), 256, 0, stream>>>(Enb, Cnb, posArr, sumexp);
    finalize_kernel<<<BB / 256, 256, 0, stream>>>(posArr, sumexp, out);
}